// Round 2
// 606.850 us; speedup vs baseline: 1.0214x; 1.0214x over previous
//
#include <hip/hip_runtime.h>
#include <math.h>

#define NROWS 524288
#define DIN 64
#define HD 128
#define DZ 16
#define KC 256
#define BETA 0.25f

#define TILE_R 64
#define NTHR 512
#define NWAVE 8

// ---- LDS layout (floats) ----
// region1: sH 64x132 (h1, then h2 in-place after a read-drain barrier); pitch 132
//          -> b128 reads: start bank = (132r+4k) % 32 = 4(r+k) % 32, 8 lanes/bank = balanced
// region0: sF 64x68 (feats tile) -> dead after phase A -> phase-C scratch overlays
#define SH_PITCH 132
#define SF_PITCH 68
#define ZPITCH 20
#define REG1_SZ (TILE_R * SH_PITCH)          // 8448
#define REG0_SZ (TILE_R * SF_PITCH)          // 4352
#define SMEM_FLOATS (REG1_SZ + REG0_SZ)      // 12800 floats = 51200 B -> 3 blocks/CU

// scratch offsets inside region0 (after sF is dead)
#define OFF_CNORM 0                             // 256
#define OFF_LVS   256                           // 64x20 = 1280 -> 1536
#define OFF_ZS    (OFF_LVS + TILE_R * ZPITCH)   // 1536, 1280 -> 2816
#define OFF_BESTD (OFF_ZS + TILE_R * ZPITCH)    // 2816, 512 -> 3328
#define OFF_BESTI (OFF_BESTD + NTHR)            // 3328, 512 -> 3840 (<= 4352)

__global__ __launch_bounds__(NTHR, 6)
void encoder_main(const float* __restrict__ feats,
                  const float* __restrict__ W1, const float* __restrict__ b1,
                  const float* __restrict__ W2, const float* __restrict__ b2,
                  const float* __restrict__ Wmu, const float* __restrict__ bmu,
                  const float* __restrict__ Wlv, const float* __restrict__ blv,
                  const float* __restrict__ codebook,
                  const float* __restrict__ eps,
                  float* __restrict__ out, float* __restrict__ loss_ws)
{
  __shared__ float smem[SMEM_FLOATS];
  float* sH = smem;                    // region1: h1 then h2 (in-place)
  float* sF = smem + REG1_SZ;          // region0: feats tile
  float* cnormS = sF + OFF_CNORM;
  float* Lvs    = sF + OFF_LVS;
  float* Zs     = sF + OFF_ZS;
  float* bestdS = sF + OFF_BESTD;
  int*   bestiS = (int*)(sF + OFF_BESTI);

  const int t = threadIdx.x;
  const int r = t & 63;                                   // row in tile == lane id
  const int wv = __builtin_amdgcn_readfirstlane(t >> 6);  // wave id 0..7, uniform
  const int row0 = blockIdx.x * TILE_R;

  // ---- stage feats tile (coalesced float4; 1024 float4 / 512 thr = 2 each) ----
  {
    const float4* __restrict__ src = (const float4*)(feats + (size_t)row0 * DIN);
    #pragma unroll
    for (int i = 0; i < 2; ++i) {
      int v = t + i * NTHR;             // float4 index 0..1023
      float4 f4 = src[v];
      int rr = v >> 4;                  // 16 float4 per row
      int cc = (v & 15) * 4;
      *(float4*)(sF + rr * SF_PITCH + cc) = f4;
    }
  }
  __syncthreads();   // barrier0: feats staged

  // ---- phase A: h1 = relu(feats @ W1 + b1); thread = (row r, 16 cols @ wv*16) ----
  {
    const int j0 = wv * 16;
    float acc[16];
    const float* __restrict__ bb = b1 + j0;               // uniform -> scalar
    #pragma unroll
    for (int i = 0; i < 16; ++i) acc[i] = bb[i];
    const float4* __restrict__ fr = (const float4*)(sF + r * SF_PITCH);
    #pragma unroll 4
    for (int k4 = 0; k4 < DIN / 4; ++k4) {
      float4 f = fr[k4];                                  // ds_read_b128, balanced banks
      const float* __restrict__ w0 = W1 + (k4 * 4 + 0) * HD + j0;  // uniform -> s_load
      const float* __restrict__ w1 = W1 + (k4 * 4 + 1) * HD + j0;
      const float* __restrict__ w2 = W1 + (k4 * 4 + 2) * HD + j0;
      const float* __restrict__ w3 = W1 + (k4 * 4 + 3) * HD + j0;
      #pragma unroll
      for (int i = 0; i < 16; ++i) acc[i] = fmaf(f.x, w0[i], acc[i]);
      #pragma unroll
      for (int i = 0; i < 16; ++i) acc[i] = fmaf(f.y, w1[i], acc[i]);
      #pragma unroll
      for (int i = 0; i < 16; ++i) acc[i] = fmaf(f.z, w2[i], acc[i]);
      #pragma unroll
      for (int i = 0; i < 16; ++i) acc[i] = fmaf(f.w, w3[i], acc[i]);
    }
    float* hrow = sH + r * SH_PITCH + j0;
    #pragma unroll
    for (int q = 0; q < 4; ++q)
      *(float4*)(hrow + 4 * q) = make_float4(fmaxf(acc[4*q+0], 0.0f), fmaxf(acc[4*q+1], 0.0f),
                                             fmaxf(acc[4*q+2], 0.0f), fmaxf(acc[4*q+3], 0.0f));
  }
  __syncthreads();   // barrier1: A done; sF dead -> scratch writable; h1 readable

  // ---- codebook norms (one code per thread, t<256; writes scratch region0) ----
  if (t < KC) {
    const float4* __restrict__ crow = (const float4*)(codebook + t * DZ);
    float4 a = crow[0], b = crow[1], c = crow[2], d = crow[3];
    cnormS[t] = a.x*a.x + a.y*a.y + a.z*a.z + a.w*a.w
              + b.x*b.x + b.y*b.y + b.z*b.z + b.w*b.w
              + c.x*c.x + c.y*c.y + c.z*c.z + c.w*c.w
              + d.x*d.x + d.y*d.y + d.z*d.z + d.w*d.w;
  }

  // ---- phase B: h2 = relu(h1 @ W2 + b2), in-place over sH ----
  {
    const int j0 = wv * 16;
    float acc[16];
    const float* __restrict__ bb = b2 + j0;
    #pragma unroll
    for (int i = 0; i < 16; ++i) acc[i] = bb[i];
    const float4* __restrict__ hr = (const float4*)(sH + r * SH_PITCH);
    #pragma unroll 4
    for (int k4 = 0; k4 < HD / 4; ++k4) {
      float4 f = hr[k4];
      const float* __restrict__ w0 = W2 + (k4 * 4 + 0) * HD + j0;
      const float* __restrict__ w1 = W2 + (k4 * 4 + 1) * HD + j0;
      const float* __restrict__ w2 = W2 + (k4 * 4 + 2) * HD + j0;
      const float* __restrict__ w3 = W2 + (k4 * 4 + 3) * HD + j0;
      #pragma unroll
      for (int i = 0; i < 16; ++i) acc[i] = fmaf(f.x, w0[i], acc[i]);
      #pragma unroll
      for (int i = 0; i < 16; ++i) acc[i] = fmaf(f.y, w1[i], acc[i]);
      #pragma unroll
      for (int i = 0; i < 16; ++i) acc[i] = fmaf(f.z, w2[i], acc[i]);
      #pragma unroll
      for (int i = 0; i < 16; ++i) acc[i] = fmaf(f.w, w3[i], acc[i]);
    }
    __syncthreads();  // barrier2: ALL h1 reads complete before overwrite
    float* hrow = sH + r * SH_PITCH + j0;
    #pragma unroll
    for (int q = 0; q < 4; ++q)
      *(float4*)(hrow + 4 * q) = make_float4(fmaxf(acc[4*q+0], 0.0f), fmaxf(acc[4*q+1], 0.0f),
                                             fmaxf(acc[4*q+2], 0.0f), fmaxf(acc[4*q+3], 0.0f));
  }
  __syncthreads();   // barrier3: h2 visible

  // ---- phase C: heads. wv0-3 -> mu (4 cols each), wv4-7 -> lv. NO global stores here. ----
  const int c0 = (wv & 3) * 4;
  const int is_mu = (wv < 4);
  const size_t zbase = (size_t)(row0 + r) * DZ + c0;
  float accC[4];
  float zv[4] = {0.0f, 0.0f, 0.0f, 0.0f};
  {
    float4 ev = make_float4(0.0f, 0.0f, 0.0f, 0.0f);
    if (is_mu) ev = *(const float4*)(eps + zbase);        // issue early; consumed after barrier4
    const float* __restrict__ Wh = is_mu ? Wmu : Wlv;
    const float* __restrict__ bh = is_mu ? bmu : blv;
    #pragma unroll
    for (int i = 0; i < 4; ++i) accC[i] = bh[c0 + i];
    const float4* __restrict__ hr = (const float4*)(sH + r * SH_PITCH);
    #pragma unroll 4
    for (int k4 = 0; k4 < HD / 4; ++k4) {
      float4 h4 = hr[k4];
      const float* __restrict__ w0 = Wh + (k4 * 4 + 0) * DZ + c0;  // uniform -> s_load
      const float* __restrict__ w1 = Wh + (k4 * 4 + 1) * DZ + c0;
      const float* __restrict__ w2 = Wh + (k4 * 4 + 2) * DZ + c0;
      const float* __restrict__ w3 = Wh + (k4 * 4 + 3) * DZ + c0;
      #pragma unroll
      for (int i = 0; i < 4; ++i) accC[i] = fmaf(h4.x, w0[i], accC[i]);
      #pragma unroll
      for (int i = 0; i < 4; ++i) accC[i] = fmaf(h4.y, w1[i], accC[i]);
      #pragma unroll
      for (int i = 0; i < 4; ++i) accC[i] = fmaf(h4.z, w2[i], accC[i]);
      #pragma unroll
      for (int i = 0; i < 4; ++i) accC[i] = fmaf(h4.w, w3[i], accC[i]);
    }
    if (!is_mu)
      *(float4*)(Lvs + r * ZPITCH + c0) = make_float4(accC[0], accC[1], accC[2], accC[3]);
    __syncthreads();   // barrier4: Lvs visible (no global stores in flight -> cheap drain)
    if (is_mu) {
      float evs[4] = {ev.x, ev.y, ev.z, ev.w};
      #pragma unroll
      for (int i = 0; i < 4; ++i) {
        float lvv = Lvs[r * ZPITCH + c0 + i];
        zv[i] = fmaf(evs[i], expf(0.5f * lvv), accC[i]);
      }
      *(float4*)(Zs + r * ZPITCH + c0) = make_float4(zv[0], zv[1], zv[2], zv[3]);
    }
    __syncthreads();   // barrier5: Zs visible
  }

  // ---- VQ: 8 threads/row, each scans 32 codes (ascending; strict < = argmin) ----
  float zreg[16];
  {
    const float4* __restrict__ zr = (const float4*)(Zs + r * ZPITCH);
    #pragma unroll
    for (int q = 0; q < 4; ++q) {
      float4 z4 = zr[q];
      zreg[4*q+0] = z4.x; zreg[4*q+1] = z4.y; zreg[4*q+2] = z4.z; zreg[4*q+3] = z4.w;
    }
  }
  {
    const int kk0 = wv * 32;
    float bd = 3.0e38f;
    int bi = kk0;
    #pragma unroll 8
    for (int c = 0; c < 32; ++c) {
      int kk = kk0 + c;
      const float* __restrict__ crow = codebook + kk * DZ;  // uniform -> s_load
      float dot = 0.0f;
      #pragma unroll
      for (int i = 0; i < 16; ++i) dot = fmaf(zreg[i], crow[i], dot);
      float s = fmaf(-2.0f, dot, cnormS[kk]);
      if (s < bd) { bd = s; bi = kk; }
    }
    bestdS[wv * 64 + r] = bd;
    bestiS[wv * 64 + r] = bi;
  }
  __syncthreads();   // barrier6 (last barrier; all global stores happen after this)

  // ---- merge (wave 0): argmin across groups, gather z_q, loss partial ----
  float lsum = 0.0f;
  float4 q0, q1, q2, q3;
  if (t < 64) {
    float bd = bestdS[r];
    int   bi = bestiS[r];
    #pragma unroll
    for (int g = 1; g < NWAVE; ++g) {   // ascending groups, strict <: lowest idx wins ties
      float d2 = bestdS[g * 64 + r];
      int   i2 = bestiS[g * 64 + r];
      if (d2 < bd) { bd = d2; bi = i2; }
    }
    const float4* __restrict__ cq = (const float4*)(codebook + bi * DZ);
    q0 = cq[0]; q1 = cq[1]; q2 = cq[2]; q3 = cq[3];
    float qq[16] = {q0.x,q0.y,q0.z,q0.w, q1.x,q1.y,q1.z,q1.w,
                    q2.x,q2.y,q2.z,q2.w, q3.x,q3.y,q3.z,q3.w};
    #pragma unroll
    for (int i = 0; i < 16; ++i) {
      float d = qq[i] - zreg[i];        // zreg IS row r's z for wave 0 (bit-exact)
      lsum = fmaf(d, d, lsum);
    }
  }

  // ---- deferred global stores (no barriers follow; kernel-end drain is free) ----
  if (t < 64) {
    const size_t base = (size_t)(row0 + r) * DZ;
    float4* __restrict__ gq = (float4*)(out + (size_t)3 * NROWS * DZ + base);
    gq[0] = q0; gq[1] = q1; gq[2] = q2; gq[3] = q3;
  }
  if (is_mu) {
    *(float4*)(out + zbase)                           = make_float4(zv[0], zv[1], zv[2], zv[3]);
    *(float4*)(out + (size_t)NROWS * DZ + zbase)      = make_float4(accC[0], accC[1], accC[2], accC[3]);
  } else {
    *(float4*)(out + (size_t)2 * NROWS * DZ + zbase)  = make_float4(accC[0], accC[1], accC[2], accC[3]);
  }

  // ---- loss partial: one atomic per block ----
  if (t < 64) {
    #pragma unroll
    for (int off = 32; off > 0; off >>= 1) lsum += __shfl_down(lsum, off);
    if (t == 0) atomicAdd(loss_ws, lsum);
  }
}

__global__ void encoder_zero(float* ws) {
  if (threadIdx.x == 0 && blockIdx.x == 0) ws[0] = 0.0f;
}

__global__ void encoder_finalize(const float* __restrict__ ws, float* __restrict__ out) {
  if (threadIdx.x == 0 && blockIdx.x == 0) {
    // vq_loss = BETA * (commit + code) = 2*BETA*mean((zq-z)^2)
    out[(size_t)4 * NROWS * DZ] = ws[0] * (2.0f * BETA / (float)((size_t)NROWS * DZ));
  }
}

extern "C" void kernel_launch(void* const* d_in, const int* in_sizes, int n_in,
                              void* d_out, int out_size, void* d_ws, size_t ws_size,
                              hipStream_t stream) {
  (void)in_sizes; (void)n_in; (void)out_size; (void)ws_size;
  const float* feats    = (const float*)d_in[0];
  const float* W1       = (const float*)d_in[1];
  const float* b1       = (const float*)d_in[2];
  const float* W2       = (const float*)d_in[3];
  const float* b2       = (const float*)d_in[4];
  const float* Wmu      = (const float*)d_in[5];
  const float* bmu      = (const float*)d_in[6];
  const float* Wlv      = (const float*)d_in[7];
  const float* blv      = (const float*)d_in[8];
  const float* codebook = (const float*)d_in[9];
  const float* eps      = (const float*)d_in[10];
  float* out = (float*)d_out;
  float* ws  = (float*)d_ws;

  hipLaunchKernelGGL(encoder_zero, dim3(1), dim3(64), 0, stream, ws);
  hipLaunchKernelGGL(encoder_main, dim3(NROWS / TILE_R), dim3(NTHR), 0, stream,
                     feats, W1, b1, W2, b2, Wmu, bmu, Wlv, blv, codebook, eps, out, ws);
  hipLaunchKernelGGL(encoder_finalize, dim3(1), dim3(64), 0, stream, ws, out);
}